// Round 2
// baseline (384.589 us; speedup 1.0000x reference)
//
#include <hip/hip_runtime.h>

#define N 9216
#define CIN 256
#define DQ 32
#define NT 144                      // N / 64
#define LOG2E 1.44269504088896340736f

typedef short short8 __attribute__((ext_vector_type(8)));   // 8 bf16 in 4 VGPRs
typedef float floatx4 __attribute__((ext_vector_type(4)));
typedef unsigned short ushort_t;

__device__ __forceinline__ ushort_t f2bf(float f) {
  union { float f; unsigned u; } a; a.f = f;
  unsigned u = a.u;
  u += 0x7fffu + ((u >> 16) & 1u);   // round-to-nearest-even
  return (ushort_t)(u >> 16);
}
__device__ __forceinline__ float bf2f(ushort_t h) {
  union { unsigned u; float f; } a; a.u = ((unsigned)h) << 16;
  return a.f;
}

// ---------------------------------------------------------------------------
// Kernel 1: q/k/v projections.  grid (144 n-tiles, 5 o-chunks), 256 threads.
// Writes qT,kT as (N, 32) bf16 rows (MFMA fragment friendly), q pre-scaled by
// log2(e) so attention can use exp2.  v kept in natural (C, N) bf16 layout.
// ---------------------------------------------------------------------------
__global__ __launch_bounds__(256) void qkv_kernel(
    const float* __restrict__ x,
    const float* __restrict__ Wq, const float* __restrict__ bq,
    const float* __restrict__ Wk, const float* __restrict__ bk,
    const float* __restrict__ Wv, const float* __restrict__ bv,
    ushort_t* __restrict__ qT, ushort_t* __restrict__ kT,
    ushort_t* __restrict__ vG)
{
  __shared__ float xs[64][68];          // stride 68: 16B-aligned rows, ~2-way banks
  const int t = threadIdx.x;
  const int n0 = blockIdx.x * 64;
  const int oc = blockIdx.y;            // 0..4 ; chunk0 = Wq(32)+Wk(32), 1..4 = Wv
  const int i = t >> 4, j = t & 15;
  const int o0 = oc * 64 + i * 4;

  const float* Wrow[4];
  float bias[4];
#pragma unroll
  for (int r = 0; r < 4; ++r) {
    const int o = o0 + r;
    if (oc == 0) {
      if (o < 32) { Wrow[r] = Wq + o * CIN;        bias[r] = bq[o]; }
      else        { Wrow[r] = Wk + (o - 32) * CIN; bias[r] = bk[o - 32]; }
    } else        { Wrow[r] = Wv + (o - 64) * CIN; bias[r] = bv[o - 64]; }
  }

  float acc[4][4] = {};
  for (int cc = 0; cc < 4; ++cc) {
    {
      const int row = t >> 2, cq = t & 3;
      const float* src = x + (size_t)(cc * 64 + row) * N + n0 + cq * 16;
      float4 a0 = *(const float4*)(src + 0);
      float4 a1 = *(const float4*)(src + 4);
      float4 a2 = *(const float4*)(src + 8);
      float4 a3 = *(const float4*)(src + 12);
      float* dst = &xs[row][cq * 16];
      *(float4*)(dst + 0) = a0; *(float4*)(dst + 4)  = a1;
      *(float4*)(dst + 8) = a2; *(float4*)(dst + 12) = a3;
    }
    __syncthreads();
#pragma unroll 2
    for (int k4 = 0; k4 < 16; ++k4) {
      float4 wv4[4];
#pragma unroll
      for (int r = 0; r < 4; ++r)
        wv4[r] = *(const float4*)(Wrow[r] + cc * 64 + k4 * 4);
#pragma unroll
      for (int kk = 0; kk < 4; ++kk) {
        float4 xv = *(const float4*)&xs[k4 * 4 + kk][j * 4];
#pragma unroll
        for (int r = 0; r < 4; ++r) {
          const float wval = ((const float*)&wv4[r])[kk];
          acc[r][0] += wval * xv.x;
          acc[r][1] += wval * xv.y;
          acc[r][2] += wval * xv.z;
          acc[r][3] += wval * xv.w;
        }
      }
    }
    __syncthreads();
  }

#pragma unroll
  for (int r = 0; r < 4; ++r) {
    const int o = o0 + r;
#pragma unroll
    for (int c = 0; c < 4; ++c) {
      const int n = n0 + j * 4 + c;
      const float val = acc[r][c] + bias[r];
      if (oc == 0) {
        if (o < 32) qT[(size_t)n * DQ + o]        = f2bf(val * LOG2E);
        else        kT[(size_t)n * DQ + (o - 32)] = f2bf(val);
      } else        vG[(size_t)(o - 64) * N + n]  = f2bf(val);
    }
  }
}

// ---------------------------------------------------------------------------
// Kernel 2: flash attention (no max-subtraction: |energy| <~ 32 in log2 domain,
// safe in fp32).  grid (144 n-tiles, nsl m-slices), 256 threads = 4 waves.
// nsl=8 when ws permits: 1152 blocks = 4.5 blocks/CU (VGPR 68 / LDS 9.2KB allow
// 8/CU, so no capacity cliff) -- occupancy was the R1 bottleneck (18%).
// Wave w: computes S rows [16w,16w+16) and accumulates O^T c-range [64w,64w+64).
//   S  = Q^T K         via mfma 16x16x32 (K = 32 = full q-depth, one MFMA)
//   O^T = V * P^T      via mfma 16x16x32, V A-frags read DIRECTLY from global
// P transits LDS (C-layout -> A/B-layout transform), stride 36 = conflict-free.
// Outputs unnormalized O^T partials (bf16) + sumexp partials per slice.
// ---------------------------------------------------------------------------
__global__ __launch_bounds__(256, 2) void attn_kernel(
    const ushort_t* __restrict__ qT, const ushort_t* __restrict__ kT,
    const ushort_t* __restrict__ vG,
    ushort_t* __restrict__ Opart, float* __restrict__ lpart,
    int sliceIters)
{
  __shared__ ushort_t Pb[2][64][36];    // double-buffered P tile (64n x 32m)

  const int t = threadIdx.x;
  const int w = t >> 6;
  const int lane = t & 63;
  const int quad = lane >> 4;
  const int l15 = lane & 15;
  const int nt = blockIdx.x;
  const int s  = blockIdx.y;
  const int n0 = nt * 64;
  const int mbase = s * sliceIters * 32;
  const int cw = w * 64;

  // Q A-fragment: invariant over the m-loop. lane holds A[m=l15][k=8*quad+j].
  short8 aq = *(const short8*)(qT + (size_t)(n0 + 16 * w + l15) * DQ + 8 * quad);

  floatx4 acc[4][4];
#pragma unroll
  for (int a2 = 0; a2 < 4; ++a2)
#pragma unroll
    for (int b2 = 0; b2 < 4; ++b2)
      acc[a2][b2] = (floatx4){0.f, 0.f, 0.f, 0.f};
  float lsum[4] = {0.f, 0.f, 0.f, 0.f};
  const floatx4 z4 = {0.f, 0.f, 0.f, 0.f};

  for (int it = 0; it < sliceIters; ++it) {
    const int m0 = mbase + it * 32;

    // S tile (16n x 32m): B-frag lane holds B[k=8*quad+j][n=l15] from kT rows.
    short8 kb0 = *(const short8*)(kT + (size_t)(m0 + l15) * DQ + 8 * quad);
    short8 kb1 = *(const short8*)(kT + (size_t)(m0 + 16 + l15) * DQ + 8 * quad);
    floatx4 s0 = __builtin_amdgcn_mfma_f32_16x16x32_bf16(aq, kb0, z4, 0, 0, 0);
    floatx4 s1 = __builtin_amdgcn_mfma_f32_16x16x32_bf16(aq, kb1, z4, 0, 0, 0);

    // V A-frags from global: A[m=c(l15)][k=m(8*quad+j)], 16B/lane, full-line use.
    const ushort_t* vb = vG + (size_t)m0 + 8 * quad;
    short8 av0 = *(const short8*)(vb + (size_t)(cw +  0 + l15) * N);
    short8 av1 = *(const short8*)(vb + (size_t)(cw + 16 + l15) * N);
    short8 av2 = *(const short8*)(vb + (size_t)(cw + 32 + l15) * N);
    short8 av3 = *(const short8*)(vb + (size_t)(cw + 48 + l15) * N);

    // exp2 (q was pre-scaled by log2e) + accumulate sumexp + write P to LDS.
    // C-layout: lane holds S[row=4*quad+r][col=l15 (+16 for s1)].
    ushort_t* pb = &Pb[it & 1][0][0];
#pragma unroll
    for (int r = 0; r < 4; ++r) {
      float p0 = exp2f(s0[r]);
      float p1 = exp2f(s1[r]);
      lsum[r] += p0 + p1;
      const int row = 16 * w + 4 * quad + r;
      pb[row * 36 + l15]      = f2bf(p0);
      pb[row * 36 + 16 + l15] = f2bf(p1);
    }
    __syncthreads();   // single barrier/iter: double buffer covers WAR hazard

    // O^T += V * P^T : B-frag lane holds P[n=b2*16+l15][m=8*quad+j].
#pragma unroll
    for (int b2 = 0; b2 < 4; ++b2) {
      const ushort_t* pr = pb + (b2 * 16 + l15) * 36 + 8 * quad;
      union { uint2 u2[2]; short8 v; } u;
      u.u2[0] = *(const uint2*)(pr);
      u.u2[1] = *(const uint2*)(pr + 4);
      const short8 pf = u.v;
      acc[0][b2] = __builtin_amdgcn_mfma_f32_16x16x32_bf16(av0, pf, acc[0][b2], 0, 0, 0);
      acc[1][b2] = __builtin_amdgcn_mfma_f32_16x16x32_bf16(av1, pf, acc[1][b2], 0, 0, 0);
      acc[2][b2] = __builtin_amdgcn_mfma_f32_16x16x32_bf16(av2, pf, acc[2][b2], 0, 0, 0);
      acc[3][b2] = __builtin_amdgcn_mfma_f32_16x16x32_bf16(av3, pf, acc[3][b2], 0, 0, 0);
    }
  }

  // sumexp: reduce over the 16 lanes sharing a quad (rows 16w + 4*quad + r)
#pragma unroll
  for (int r = 0; r < 4; ++r) {
    float v = lsum[r];
    v += __shfl_xor(v, 1);
    v += __shfl_xor(v, 2);
    v += __shfl_xor(v, 4);
    v += __shfl_xor(v, 8);
    lsum[r] = v;
  }
  if (l15 == 0) {
#pragma unroll
    for (int r = 0; r < 4; ++r)
      lpart[(size_t)s * N + n0 + 16 * w + 4 * quad + r] = lsum[r];
  }

  // store O^T partial, layout [s][nt][c:256][n:64]; C-layout cols = n => coalesced
  const size_t base = ((size_t)s * NT + nt) * 256;
#pragma unroll
  for (int a2 = 0; a2 < 4; ++a2)
#pragma unroll
    for (int b2 = 0; b2 < 4; ++b2)
#pragma unroll
      for (int r = 0; r < 4; ++r) {
        const int c  = cw + a2 * 16 + 4 * quad + r;
        const int nl = b2 * 16 + l15;
        Opart[(base + c) * 64 + nl] = f2bf(acc[a2][b2][r]);
      }
}

// ---------------------------------------------------------------------------
// Kernel 3: combine m-slice partials -> out_co[n] = (max_c + mean_c)/sumexp
// ---------------------------------------------------------------------------
__global__ __launch_bounds__(256) void combine_kernel(
    const ushort_t* __restrict__ Opart, const float* __restrict__ lpart,
    float* __restrict__ out_co, int nsl)
{
  const int nt = blockIdx.x, t = threadIdx.x;
  const int n = t & 63, cg = t >> 6;
  float mx = -3.4e38f, sm = 0.f;
  for (int ci = 0; ci < 64; ++ci) {
    const int c = cg * 64 + ci;
    float val = 0.f;
    for (int s2 = 0; s2 < nsl; ++s2)
      val += bf2f(Opart[(((size_t)s2 * NT + nt) * 256 + c) * 64 + n]);
    mx = fmaxf(mx, val);
    sm += val;
  }
  __shared__ float rmx[256], rsm[256];
  rmx[t] = mx; rsm[t] = sm;
  __syncthreads();
  if (t < 64) {
    const float m2 = fmaxf(fmaxf(rmx[t], rmx[t + 64]), fmaxf(rmx[t + 128], rmx[t + 192]));
    const float s2 = rsm[t] + rsm[t + 64] + rsm[t + 128] + rsm[t + 192];
    const int gn = nt * 64 + t;
    float l = 0.f;
    for (int s3 = 0; s3 < nsl; ++s3) l += lpart[s3 * N + gn];
    out_co[gn] = (m2 + s2 * (1.0f / 256.0f)) / l;
  }
}

// ---------------------------------------------------------------------------
// Kernel 4: spatial gate  x_co = softmax(out_co * C^-0.5)  (one block, N=9216)
// ---------------------------------------------------------------------------
__global__ __launch_bounds__(1024) void gate_kernel(
    const float* __restrict__ out_co, float* __restrict__ x_co)
{
  const int t = threadIdx.x;
  float z[9];
#pragma unroll
  for (int i2 = 0; i2 < 9; ++i2) z[i2] = out_co[t + 1024 * i2] * 0.0625f;
  float mx = z[0];
#pragma unroll
  for (int i2 = 1; i2 < 9; ++i2) mx = fmaxf(mx, z[i2]);
  for (int off = 32; off > 0; off >>= 1) mx = fmaxf(mx, __shfl_xor(mx, off));
  __shared__ float redm[16], reds[16];
  const int wv = t >> 6, ln = t & 63;
  if (ln == 0) redm[wv] = mx;
  __syncthreads();
  mx = redm[0];
#pragma unroll
  for (int i2 = 1; i2 < 16; ++i2) mx = fmaxf(mx, redm[i2]);

  float e[9]; float sm = 0.f;
#pragma unroll
  for (int i2 = 0; i2 < 9; ++i2) { e[i2] = exp2f((z[i2] - mx) * LOG2E); sm += e[i2]; }
  for (int off = 32; off > 0; off >>= 1) sm += __shfl_xor(sm, off);
  if (ln == 0) reds[wv] = sm;
  __syncthreads();
  sm = 0.f;
#pragma unroll
  for (int i2 = 0; i2 < 16; ++i2) sm += reds[i2];
  const float inv = 1.0f / sm;
#pragma unroll
  for (int i2 = 0; i2 < 9; ++i2) x_co[t + 1024 * i2] = e[i2] * inv;
}

// ---------------------------------------------------------------------------
// Kernel 5: out = x + (1+gamma)*(x_co[n]*(W6@x)[o][n] + b6[o])
// (x_co factors out of the channel sum.)  grid (144, 4), 256 threads.
// ---------------------------------------------------------------------------
__global__ __launch_bounds__(256) void final_kernel(
    const float* __restrict__ x, const float* __restrict__ W6,
    const float* __restrict__ b6, const float* __restrict__ gamma,
    const float* __restrict__ x_co, float* __restrict__ out)
{
  __shared__ float xs[64][68];
  const int t = threadIdx.x;
  const int n0 = blockIdx.x * 64;
  const int i = t >> 4, j = t & 15;
  const int o0 = blockIdx.y * 64 + i * 4;

  float acc[4][4] = {};
  for (int cc = 0; cc < 4; ++cc) {
    {
      const int row = t >> 2, cq = t & 3;
      const float* src = x + (size_t)(cc * 64 + row) * N + n0 + cq * 16;
      float4 a0 = *(const float4*)(src + 0);
      float4 a1 = *(const float4*)(src + 4);
      float4 a2 = *(const float4*)(src + 8);
      float4 a3 = *(const float4*)(src + 12);
      float* dst = &xs[row][cq * 16];
      *(float4*)(dst + 0) = a0; *(float4*)(dst + 4)  = a1;
      *(float4*)(dst + 8) = a2; *(float4*)(dst + 12) = a3;
    }
    __syncthreads();
#pragma unroll 2
    for (int k4 = 0; k4 < 16; ++k4) {
      float4 wv4[4];
#pragma unroll
      for (int r = 0; r < 4; ++r)
        wv4[r] = *(const float4*)(W6 + (size_t)(o0 + r) * CIN + cc * 64 + k4 * 4);
#pragma unroll
      for (int kk = 0; kk < 4; ++kk) {
        float4 xv = *(const float4*)&xs[k4 * 4 + kk][j * 4];
#pragma unroll
        for (int r = 0; r < 4; ++r) {
          const float wval = ((const float*)&wv4[r])[kk];
          acc[r][0] += wval * xv.x;
          acc[r][1] += wval * xv.y;
          acc[r][2] += wval * xv.z;
          acc[r][3] += wval * xv.w;
        }
      }
    }
    __syncthreads();
  }

  const float g1 = 1.0f + gamma[0];
  const float4 xc = *(const float4*)(x_co + n0 + j * 4);
#pragma unroll
  for (int r = 0; r < 4; ++r) {
    const int o = o0 + r;
    const float bv6 = b6[o];
    const float4 xrow = *(const float4*)(x + (size_t)o * N + n0 + j * 4);
    float4 res;
    res.x = xrow.x + g1 * (xc.x * acc[r][0] + bv6);
    res.y = xrow.y + g1 * (xc.y * acc[r][1] + bv6);
    res.z = xrow.z + g1 * (xc.z * acc[r][2] + bv6);
    res.w = xrow.w + g1 * (xc.w * acc[r][3] + bv6);
    *(float4*)(out + (size_t)o * N + n0 + j * 4) = res;
  }
}

// ---------------------------------------------------------------------------
extern "C" void kernel_launch(void* const* d_in, const int* in_sizes, int n_in,
                              void* d_out, int out_size, void* d_ws, size_t ws_size,
                              hipStream_t stream)
{
  const float* x     = (const float*)d_in[0];
  const float* Wq    = (const float*)d_in[1];
  const float* bq    = (const float*)d_in[2];
  const float* Wk    = (const float*)d_in[3];
  const float* bk    = (const float*)d_in[4];
  const float* Wv    = (const float*)d_in[5];
  const float* bv    = (const float*)d_in[6];
  const float* W6    = (const float*)d_in[7];
  const float* b6    = (const float*)d_in[8];
  const float* gamma = (const float*)d_in[9];
  float* out = (float*)d_out;

  // nsl = 8 gives 1152 attn blocks (4.5/CU, no capacity cliff at 8/CU).
  // Fall back to the proven nsl = 4 if the workspace can't hold Opart.
  const size_t fixed = (size_t)N * DQ * 2 * 2      // qT,kT
                     + (size_t)CIN * N * 2          // vG
                     + (size_t)N * 4 + (size_t)N * 4; // out_co, x_co
  int nsl = 8;
  size_t need8 = fixed + (size_t)8 * NT * 256 * 64 * 2 + (size_t)8 * N * 4;
  if (ws_size < need8) nsl = 4;
  const int sliceIters = (N / nsl) / 32;

  char* ws = (char*)d_ws;
  const size_t OFF_QT = 0;
  const size_t OFF_KT = OFF_QT + (size_t)N * DQ * 2;
  const size_t OFF_V  = OFF_KT + (size_t)N * DQ * 2;
  const size_t OFF_OP = OFF_V  + (size_t)CIN * N * 2;
  const size_t OFF_LP = OFF_OP + (size_t)nsl * NT * 256 * 64 * 2;
  const size_t OFF_OC = OFF_LP + (size_t)nsl * N * 4;
  const size_t OFF_XC = OFF_OC + (size_t)N * 4;

  ushort_t* qT     = (ushort_t*)(ws + OFF_QT);
  ushort_t* kT     = (ushort_t*)(ws + OFF_KT);
  ushort_t* vG     = (ushort_t*)(ws + OFF_V);
  ushort_t* Opart  = (ushort_t*)(ws + OFF_OP);
  float*    lpart  = (float*)(ws + OFF_LP);
  float*    out_co = (float*)(ws + OFF_OC);
  float*    x_co   = (float*)(ws + OFF_XC);

  qkv_kernel<<<dim3(NT, 5), 256, 0, stream>>>(x, Wq, bq, Wk, bk, Wv, bv, qT, kT, vG);
  attn_kernel<<<dim3(NT, nsl), 256, 0, stream>>>(qT, kT, vG, Opart, lpart, sliceIters);
  combine_kernel<<<NT, 256, 0, stream>>>(Opart, lpart, out_co, nsl);
  gate_kernel<<<1, 1024, 0, stream>>>(out_co, x_co);
  final_kernel<<<dim3(NT, 4), 256, 0, stream>>>(x, W6, b6, gamma, x_co, out);
}

// Round 3
// 255.396 us; speedup vs baseline: 1.5059x; 1.5059x over previous
//
#include <hip/hip_runtime.h>

#define N 9216
#define CIN 256
#define DQ 32
#define NT 144                      // N / 64
#define LOG2E 1.44269504088896340736f

typedef short short8 __attribute__((ext_vector_type(8)));   // 8 bf16 in 4 VGPRs
typedef float floatx4 __attribute__((ext_vector_type(4)));
typedef unsigned short ushort_t;

__device__ __forceinline__ ushort_t f2bf(float f) {
  union { float f; unsigned u; } a; a.f = f;
  unsigned u = a.u;
  u += 0x7fffu + ((u >> 16) & 1u);   // round-to-nearest-even
  return (ushort_t)(u >> 16);
}
__device__ __forceinline__ float bf2f(ushort_t h) {
  union { unsigned u; float f; } a; a.u = ((unsigned)h) << 16;
  return a.f;
}

// ---------------------------------------------------------------------------
// Kernel 1: q/k/v projections.  grid (144 n-tiles, 5 o-chunks), 256 threads.
// ---------------------------------------------------------------------------
__global__ __launch_bounds__(256) void qkv_kernel(
    const float* __restrict__ x,
    const float* __restrict__ Wq, const float* __restrict__ bq,
    const float* __restrict__ Wk, const float* __restrict__ bk,
    const float* __restrict__ Wv, const float* __restrict__ bv,
    ushort_t* __restrict__ qT, ushort_t* __restrict__ kT,
    ushort_t* __restrict__ vG)
{
  __shared__ float xs[64][68];          // stride 68: 16B-aligned rows, ~2-way banks
  const int t = threadIdx.x;
  const int n0 = blockIdx.x * 64;
  const int oc = blockIdx.y;            // 0..4 ; chunk0 = Wq(32)+Wk(32), 1..4 = Wv
  const int i = t >> 4, j = t & 15;
  const int o0 = oc * 64 + i * 4;

  const float* Wrow[4];
  float bias[4];
#pragma unroll
  for (int r = 0; r < 4; ++r) {
    const int o = o0 + r;
    if (oc == 0) {
      if (o < 32) { Wrow[r] = Wq + o * CIN;        bias[r] = bq[o]; }
      else        { Wrow[r] = Wk + (o - 32) * CIN; bias[r] = bk[o - 32]; }
    } else        { Wrow[r] = Wv + (o - 64) * CIN; bias[r] = bv[o - 64]; }
  }

  float acc[4][4] = {};
  for (int cc = 0; cc < 4; ++cc) {
    {
      const int row = t >> 2, cq = t & 3;
      const float* src = x + (size_t)(cc * 64 + row) * N + n0 + cq * 16;
      float4 a0 = *(const float4*)(src + 0);
      float4 a1 = *(const float4*)(src + 4);
      float4 a2 = *(const float4*)(src + 8);
      float4 a3 = *(const float4*)(src + 12);
      float* dst = &xs[row][cq * 16];
      *(float4*)(dst + 0) = a0; *(float4*)(dst + 4)  = a1;
      *(float4*)(dst + 8) = a2; *(float4*)(dst + 12) = a3;
    }
    __syncthreads();
#pragma unroll 2
    for (int k4 = 0; k4 < 16; ++k4) {
      float4 wv4[4];
#pragma unroll
      for (int r = 0; r < 4; ++r)
        wv4[r] = *(const float4*)(Wrow[r] + cc * 64 + k4 * 4);
#pragma unroll
      for (int kk = 0; kk < 4; ++kk) {
        float4 xv = *(const float4*)&xs[k4 * 4 + kk][j * 4];
#pragma unroll
        for (int r = 0; r < 4; ++r) {
          const float wval = ((const float*)&wv4[r])[kk];
          acc[r][0] += wval * xv.x;
          acc[r][1] += wval * xv.y;
          acc[r][2] += wval * xv.z;
          acc[r][3] += wval * xv.w;
        }
      }
    }
    __syncthreads();
  }

#pragma unroll
  for (int r = 0; r < 4; ++r) {
    const int o = o0 + r;
#pragma unroll
    for (int c = 0; c < 4; ++c) {
      const int n = n0 + j * 4 + c;
      const float val = acc[r][c] + bias[r];
      if (oc == 0) {
        if (o < 32) qT[(size_t)n * DQ + o]        = f2bf(val * LOG2E);
        else        kT[(size_t)n * DQ + (o - 32)] = f2bf(val);
      } else        vG[(size_t)(o - 64) * N + n]  = f2bf(val);
    }
  }
}

// ---------------------------------------------------------------------------
// Kernel 2: flash attention.  grid (144 n-tiles, nsl m-slices), 256 thr.
// ---------------------------------------------------------------------------
__global__ __launch_bounds__(256, 2) void attn_kernel(
    const ushort_t* __restrict__ qT, const ushort_t* __restrict__ kT,
    const ushort_t* __restrict__ vG,
    ushort_t* __restrict__ Opart, float* __restrict__ lpart,
    int sliceIters)
{
  __shared__ ushort_t Pb[2][64][36];    // double-buffered P tile (64n x 32m)

  const int t = threadIdx.x;
  const int w = t >> 6;
  const int lane = t & 63;
  const int quad = lane >> 4;
  const int l15 = lane & 15;
  const int nt = blockIdx.x;
  const int s  = blockIdx.y;
  const int n0 = nt * 64;
  const int mbase = s * sliceIters * 32;
  const int cw = w * 64;

  // Q A-fragment: invariant over the m-loop. lane holds A[m=l15][k=8*quad+j].
  short8 aq = *(const short8*)(qT + (size_t)(n0 + 16 * w + l15) * DQ + 8 * quad);

  floatx4 acc[4][4];
#pragma unroll
  for (int a2 = 0; a2 < 4; ++a2)
#pragma unroll
    for (int b2 = 0; b2 < 4; ++b2)
      acc[a2][b2] = (floatx4){0.f, 0.f, 0.f, 0.f};
  float lsum[4] = {0.f, 0.f, 0.f, 0.f};
  const floatx4 z4 = {0.f, 0.f, 0.f, 0.f};

  for (int it = 0; it < sliceIters; ++it) {
    const int m0 = mbase + it * 32;

    // S tile (16n x 32m): B-frag lane holds B[k=8*quad+j][n=l15] from kT rows.
    short8 kb0 = *(const short8*)(kT + (size_t)(m0 + l15) * DQ + 8 * quad);
    short8 kb1 = *(const short8*)(kT + (size_t)(m0 + 16 + l15) * DQ + 8 * quad);
    floatx4 s0 = __builtin_amdgcn_mfma_f32_16x16x32_bf16(aq, kb0, z4, 0, 0, 0);
    floatx4 s1 = __builtin_amdgcn_mfma_f32_16x16x32_bf16(aq, kb1, z4, 0, 0, 0);

    // V A-frags from global: A[m=c(l15)][k=m(8*quad+j)], 16B/lane.
    const ushort_t* vb = vG + (size_t)m0 + 8 * quad;
    short8 av0 = *(const short8*)(vb + (size_t)(cw +  0 + l15) * N);
    short8 av1 = *(const short8*)(vb + (size_t)(cw + 16 + l15) * N);
    short8 av2 = *(const short8*)(vb + (size_t)(cw + 32 + l15) * N);
    short8 av3 = *(const short8*)(vb + (size_t)(cw + 48 + l15) * N);

    // exp2 (q pre-scaled by log2e) + sumexp + P -> LDS.
    ushort_t* pb = &Pb[it & 1][0][0];
#pragma unroll
    for (int r = 0; r < 4; ++r) {
      float p0 = exp2f(s0[r]);
      float p1 = exp2f(s1[r]);
      lsum[r] += p0 + p1;
      const int row = 16 * w + 4 * quad + r;
      pb[row * 36 + l15]      = f2bf(p0);
      pb[row * 36 + 16 + l15] = f2bf(p1);
    }
    __syncthreads();   // single barrier/iter: double buffer covers WAR hazard

    // O^T += V * P^T : B-frag lane holds P[n=b2*16+l15][m=8*quad+j].
#pragma unroll
    for (int b2 = 0; b2 < 4; ++b2) {
      const ushort_t* pr = pb + (b2 * 16 + l15) * 36 + 8 * quad;
      union { uint2 u2[2]; short8 v; } u;
      u.u2[0] = *(const uint2*)(pr);
      u.u2[1] = *(const uint2*)(pr + 4);
      const short8 pf = u.v;
      acc[0][b2] = __builtin_amdgcn_mfma_f32_16x16x32_bf16(av0, pf, acc[0][b2], 0, 0, 0);
      acc[1][b2] = __builtin_amdgcn_mfma_f32_16x16x32_bf16(av1, pf, acc[1][b2], 0, 0, 0);
      acc[2][b2] = __builtin_amdgcn_mfma_f32_16x16x32_bf16(av2, pf, acc[2][b2], 0, 0, 0);
      acc[3][b2] = __builtin_amdgcn_mfma_f32_16x16x32_bf16(av3, pf, acc[3][b2], 0, 0, 0);
    }
  }

  // sumexp: reduce over the 16 lanes sharing a quad
#pragma unroll
  for (int r = 0; r < 4; ++r) {
    float v = lsum[r];
    v += __shfl_xor(v, 1);
    v += __shfl_xor(v, 2);
    v += __shfl_xor(v, 4);
    v += __shfl_xor(v, 8);
    lsum[r] = v;
  }
  if (l15 == 0) {
#pragma unroll
    for (int r = 0; r < 4; ++r)
      lpart[(size_t)s * N + n0 + 16 * w + 4 * quad + r] = lsum[r];
  }

  // store O^T partial, layout [s][nt][c:256][n:64]
  const size_t base = ((size_t)s * NT + nt) * 256;
#pragma unroll
  for (int a2 = 0; a2 < 4; ++a2)
#pragma unroll
    for (int b2 = 0; b2 < 4; ++b2)
#pragma unroll
      for (int r = 0; r < 4; ++r) {
        const int c  = cw + a2 * 16 + 4 * quad + r;
        const int nl = b2 * 16 + l15;
        Opart[(base + c) * 64 + nl] = f2bf(acc[a2][b2][r]);
      }
}

// ---------------------------------------------------------------------------
// Kernel 3a: combine stage A.  grid (144 n-tiles, 8 c-groups) = 1152 blocks
// (R2's combine was 144 blocks = 0.56/CU, pure latency-bound at 135 GB/s).
// Each block: sum Opart over slices for 32 channels x 64 n, partial max/sum
// over its channels -> pmax/psum[cgroup][n].  64 independent 2B coalesced
// loads per thread (full 128B line per wave) for ILP.
// ---------------------------------------------------------------------------
__global__ __launch_bounds__(256) void cco_partial(
    const ushort_t* __restrict__ Opart,
    float* __restrict__ pmax, float* __restrict__ psum, int nsl)
{
  const int nt = blockIdx.x, cy = blockIdx.y;
  const int t = threadIdx.x;
  const int n = t & 63, ci = t >> 6;
  float mx = -3.4e38f, sm = 0.f;
#pragma unroll
  for (int k = 0; k < 8; ++k) {
    const int c = cy * 32 + ci + 4 * k;
    float val = 0.f;
#pragma unroll 8
    for (int s2 = 0; s2 < nsl; ++s2)
      val += bf2f(Opart[(((size_t)s2 * NT + nt) * 256 + c) * 64 + n]);
    mx = fmaxf(mx, val);
    sm += val;
  }
  __shared__ float rmx[4][64], rsm[4][64];
  rmx[ci][n] = mx; rsm[ci][n] = sm;
  __syncthreads();
  if (t < 64) {
    const float m2 = fmaxf(fmaxf(rmx[0][t], rmx[1][t]), fmaxf(rmx[2][t], rmx[3][t]));
    const float s2 = rsm[0][t] + rsm[1][t] + rsm[2][t] + rsm[3][t];
    pmax[(size_t)cy * N + nt * 64 + t] = m2;
    psum[(size_t)cy * N + nt * 64 + t] = s2;
  }
}

// ---------------------------------------------------------------------------
// Kernel 3b: combine stage B.  out_co[n] = (max + mean/256) / sumexp.
// 36 blocks x 256 threads, all loads coalesced.
// ---------------------------------------------------------------------------
__global__ __launch_bounds__(256) void cco_final(
    const float* __restrict__ pmax, const float* __restrict__ psum,
    const float* __restrict__ lpart, float* __restrict__ out_co, int nsl)
{
  const int n = blockIdx.x * 256 + threadIdx.x;
  float m = -3.4e38f, s = 0.f, l = 0.f;
#pragma unroll
  for (int g = 0; g < 8; ++g) {
    m = fmaxf(m, pmax[(size_t)g * N + n]);
    s += psum[(size_t)g * N + n];
  }
#pragma unroll 8
  for (int s3 = 0; s3 < nsl; ++s3) l += lpart[(size_t)s3 * N + n];
  out_co[n] = (m + s * (1.0f / 256.0f)) / l;
}

// ---------------------------------------------------------------------------
// Kernel 4: spatial gate  x_co = softmax(out_co * C^-0.5)  (one block)
// ---------------------------------------------------------------------------
__global__ __launch_bounds__(1024) void gate_kernel(
    const float* __restrict__ out_co, float* __restrict__ x_co)
{
  const int t = threadIdx.x;
  float z[9];
#pragma unroll
  for (int i2 = 0; i2 < 9; ++i2) z[i2] = out_co[t + 1024 * i2] * 0.0625f;
  float mx = z[0];
#pragma unroll
  for (int i2 = 1; i2 < 9; ++i2) mx = fmaxf(mx, z[i2]);
  for (int off = 32; off > 0; off >>= 1) mx = fmaxf(mx, __shfl_xor(mx, off));
  __shared__ float redm[16], reds[16];
  const int wv = t >> 6, ln = t & 63;
  if (ln == 0) redm[wv] = mx;
  __syncthreads();
  mx = redm[0];
#pragma unroll
  for (int i2 = 1; i2 < 16; ++i2) mx = fmaxf(mx, redm[i2]);

  float e[9]; float sm = 0.f;
#pragma unroll
  for (int i2 = 0; i2 < 9; ++i2) { e[i2] = exp2f((z[i2] - mx) * LOG2E); sm += e[i2]; }
  for (int off = 32; off > 0; off >>= 1) sm += __shfl_xor(sm, off);
  if (ln == 0) reds[wv] = sm;
  __syncthreads();
  sm = 0.f;
#pragma unroll
  for (int i2 = 0; i2 < 16; ++i2) sm += reds[i2];
  const float inv = 1.0f / sm;
#pragma unroll
  for (int i2 = 0; i2 < 9; ++i2) x_co[t + 1024 * i2] = e[i2] * inv;
}

// ---------------------------------------------------------------------------
// Kernel 5: out = x + (1+gamma)*(x_co[n]*(W6@x)[o][n] + b6[o])
// ---------------------------------------------------------------------------
__global__ __launch_bounds__(256) void final_kernel(
    const float* __restrict__ x, const float* __restrict__ W6,
    const float* __restrict__ b6, const float* __restrict__ gamma,
    const float* __restrict__ x_co, float* __restrict__ out)
{
  __shared__ float xs[64][68];
  const int t = threadIdx.x;
  const int n0 = blockIdx.x * 64;
  const int i = t >> 4, j = t & 15;
  const int o0 = blockIdx.y * 64 + i * 4;

  float acc[4][4] = {};
  for (int cc = 0; cc < 4; ++cc) {
    {
      const int row = t >> 2, cq = t & 3;
      const float* src = x + (size_t)(cc * 64 + row) * N + n0 + cq * 16;
      float4 a0 = *(const float4*)(src + 0);
      float4 a1 = *(const float4*)(src + 4);
      float4 a2 = *(const float4*)(src + 8);
      float4 a3 = *(const float4*)(src + 12);
      float* dst = &xs[row][cq * 16];
      *(float4*)(dst + 0) = a0; *(float4*)(dst + 4)  = a1;
      *(float4*)(dst + 8) = a2; *(float4*)(dst + 12) = a3;
    }
    __syncthreads();
#pragma unroll 2
    for (int k4 = 0; k4 < 16; ++k4) {
      float4 wv4[4];
#pragma unroll
      for (int r = 0; r < 4; ++r)
        wv4[r] = *(const float4*)(W6 + (size_t)(o0 + r) * CIN + cc * 64 + k4 * 4);
#pragma unroll
      for (int kk = 0; kk < 4; ++kk) {
        float4 xv = *(const float4*)&xs[k4 * 4 + kk][j * 4];
#pragma unroll
        for (int r = 0; r < 4; ++r) {
          const float wval = ((const float*)&wv4[r])[kk];
          acc[r][0] += wval * xv.x;
          acc[r][1] += wval * xv.y;
          acc[r][2] += wval * xv.z;
          acc[r][3] += wval * xv.w;
        }
      }
    }
    __syncthreads();
  }

  const float g1 = 1.0f + gamma[0];
  const float4 xc = *(const float4*)(x_co + n0 + j * 4);
#pragma unroll
  for (int r = 0; r < 4; ++r) {
    const int o = o0 + r;
    const float bv6 = b6[o];
    const float4 xrow = *(const float4*)(x + (size_t)o * N + n0 + j * 4);
    float4 res;
    res.x = xrow.x + g1 * (xc.x * acc[r][0] + bv6);
    res.y = xrow.y + g1 * (xc.y * acc[r][1] + bv6);
    res.z = xrow.z + g1 * (xc.z * acc[r][2] + bv6);
    res.w = xrow.w + g1 * (xc.w * acc[r][3] + bv6);
    *(float4*)(out + (size_t)o * N + n0 + j * 4) = res;
  }
}

// ---------------------------------------------------------------------------
extern "C" void kernel_launch(void* const* d_in, const int* in_sizes, int n_in,
                              void* d_out, int out_size, void* d_ws, size_t ws_size,
                              hipStream_t stream)
{
  const float* x     = (const float*)d_in[0];
  const float* Wq    = (const float*)d_in[1];
  const float* bq    = (const float*)d_in[2];
  const float* Wk    = (const float*)d_in[3];
  const float* bk    = (const float*)d_in[4];
  const float* Wv    = (const float*)d_in[5];
  const float* bv    = (const float*)d_in[6];
  const float* W6    = (const float*)d_in[7];
  const float* b6    = (const float*)d_in[8];
  const float* gamma = (const float*)d_in[9];
  float* out = (float*)d_out;

  // nsl = 8 -> 1152 attn blocks (4.5/CU).  Fallback nsl = 4 if ws too small.
  const size_t fixed = (size_t)N * DQ * 2 * 2        // qT,kT
                     + (size_t)CIN * N * 2            // vG
                     + (size_t)N * 4 * 2              // out_co, x_co
                     + (size_t)8 * N * 4 * 2;         // pmax, psum
  int nsl = 8;
  size_t need8 = fixed + (size_t)8 * NT * 256 * 64 * 2 + (size_t)8 * N * 4;
  if (ws_size < need8) nsl = 4;
  const int sliceIters = (N / nsl) / 32;

  char* ws = (char*)d_ws;
  const size_t OFF_QT = 0;
  const size_t OFF_KT = OFF_QT + (size_t)N * DQ * 2;
  const size_t OFF_V  = OFF_KT + (size_t)N * DQ * 2;
  const size_t OFF_OP = OFF_V  + (size_t)CIN * N * 2;
  const size_t OFF_LP = OFF_OP + (size_t)nsl * NT * 256 * 64 * 2;
  const size_t OFF_PM = OFF_LP + (size_t)nsl * N * 4;
  const size_t OFF_PS = OFF_PM + (size_t)8 * N * 4;
  const size_t OFF_OC = OFF_PS + (size_t)8 * N * 4;
  const size_t OFF_XC = OFF_OC + (size_t)N * 4;

  ushort_t* qT     = (ushort_t*)(ws + OFF_QT);
  ushort_t* kT     = (ushort_t*)(ws + OFF_KT);
  ushort_t* vG     = (ushort_t*)(ws + OFF_V);
  ushort_t* Opart  = (ushort_t*)(ws + OFF_OP);
  float*    lpart  = (float*)(ws + OFF_LP);
  float*    pmax   = (float*)(ws + OFF_PM);
  float*    psum   = (float*)(ws + OFF_PS);
  float*    out_co = (float*)(ws + OFF_OC);
  float*    x_co   = (float*)(ws + OFF_XC);

  qkv_kernel<<<dim3(NT, 5), 256, 0, stream>>>(x, Wq, bq, Wk, bk, Wv, bv, qT, kT, vG);
  attn_kernel<<<dim3(NT, nsl), 256, 0, stream>>>(qT, kT, vG, Opart, lpart, sliceIters);
  cco_partial<<<dim3(NT, 8), 256, 0, stream>>>(Opart, pmax, psum, nsl);
  cco_final<<<N / 256, 256, 0, stream>>>(pmax, psum, lpart, out_co, nsl);
  gate_kernel<<<1, 1024, 0, stream>>>(out_co, x_co);
  final_kernel<<<dim3(NT, 4), 256, 0, stream>>>(x, W6, b6, gamma, x_co, out);
}